// Round 10
// baseline (1481.693 us; speedup 1.0000x reference)
//
#include <hip/hip_runtime.h>

#define NUM_USERS  150000
#define NUM_ITEMS  140000
#define NUM_BRANDS 10000
#define N_NODES    300000
#define DIM        64
#define N_EDGES    1200000
#define OUT_ROWS   290000          // users + items

#define CHUNK      1024            // elements per scan block
#define NB         ((N_NODES + CHUNK - 1) / CHUNK)   // 293 scan blocks

#define NBIN       8               // one bin per XCD
#define BINSZ      (N_EDGES / NBIN)                  // 150000 csr records/bin
#define NDEG       64              // degree buckets for counting sort

// ---------------------------------------------------------------------------
// bf16 helpers (h1/h2 stored as packed bf16: 64 dims = 8 uint4 per row)
// ---------------------------------------------------------------------------
__device__ __forceinline__ float bf_lo(unsigned u) { return __uint_as_float(u << 16); }
__device__ __forceinline__ float bf_hi(unsigned u) { return __uint_as_float(u & 0xffff0000u); }
__device__ __forceinline__ unsigned pack_bf(float a, float b) {
    unsigned ua = __float_as_uint(a); ua += 0x7fffu + ((ua >> 16) & 1u);
    unsigned ub = __float_as_uint(b); ub += 0x7fffu + ((ub >> 16) & 1u);
    return (ua >> 16) | (ub & 0xffff0000u);
}

// ---------------------------------------------------------------------------
// histogram of destination degrees + per-edge rank within its row
// ---------------------------------------------------------------------------
__global__ void lgcn_hist(const int* __restrict__ dst,
                          int* __restrict__ counts,
                          int* __restrict__ rank) {
    int e = blockIdx.x * blockDim.x + threadIdx.x;
    if (e >= N_EDGES) return;
    rank[e] = atomicAdd(&counts[dst[e]], 1);
}

// ---------------------------------------------------------------------------
// scan phase 1: per-1024-chunk exclusive scan (256 thr x 4 elem), chunk sums
// ---------------------------------------------------------------------------
__global__ void lgcn_scan_p1(const int* __restrict__ counts,
                             int* __restrict__ rowptr,
                             int* __restrict__ blockSums) {
    __shared__ int ts[256];
    int b    = blockIdx.x;
    int base = b * CHUNK;
    int t    = threadIdx.x;
    int c[4];
    int s = 0;
#pragma unroll
    for (int i = 0; i < 4; ++i) {
        int g = base + t * 4 + i;
        c[i] = (g < N_NODES) ? counts[g] : 0;
        s += c[i];
    }
    ts[t] = s;
    __syncthreads();
    for (int off = 1; off < 256; off <<= 1) {
        int v = (t >= off) ? ts[t - off] : 0;
        __syncthreads();
        ts[t] += v;
        __syncthreads();
    }
    int run = ts[t] - s;     // exclusive prefix of this thread's 4-group
#pragma unroll
    for (int i = 0; i < 4; ++i) {
        int g = base + t * 4 + i;
        if (g < N_NODES) rowptr[g] = run;
        run += c[i];
    }
    if (t == 255) blockSums[b] = ts[255];
}

// ---------------------------------------------------------------------------
// scan phase 2: single block exclusive-scans the NB (=293) chunk sums
// ---------------------------------------------------------------------------
__global__ void lgcn_scan_p2(int* __restrict__ blockSums) {
    __shared__ int sh[512];
    int t = threadIdx.x;
    int v = (t < NB) ? blockSums[t] : 0;
    sh[t] = v;
    __syncthreads();
    for (int off = 1; off < 512; off <<= 1) {
        int u = (t >= off) ? sh[t - off] : 0;
        __syncthreads();
        sh[t] += u;
        __syncthreads();
    }
    if (t < NB) blockSums[t] = sh[t] - v;   // exclusive
}

// ---------------------------------------------------------------------------
// scan phase 3: add chunk offsets; rowptr[N_NODES] = N_EDGES
// ---------------------------------------------------------------------------
__global__ void lgcn_scan_p3(int* __restrict__ rowptr,
                             const int* __restrict__ blockSums) {
    int b    = blockIdx.x;
    int base = b * CHUNK;
    int t    = threadIdx.x;
    int off  = blockSums[b];
#pragma unroll
    for (int i = 0; i < 4; ++i) {
        int g = base + t * 4 + i;
        if (g < N_NODES) rowptr[g] += off;
    }
    if (b == 0 && t == 0) rowptr[N_NODES] = N_EDGES;
}

// ---------------------------------------------------------------------------
// degree counting sort (deterministic values; bucket order run-varying but
// output is node-indexed so results are identical):
//   degbin: drank[n] = rank within degree bucket
//   degscan: 64-entry exclusive scan (one wave, shfl)
//   order:  order[degOff[d] + drank[n]] = n
// ---------------------------------------------------------------------------
__global__ void lgcn_degbin(const int* __restrict__ counts,
                            int* __restrict__ degHist,
                            int* __restrict__ drank) {
    int n = blockIdx.x * blockDim.x + threadIdx.x;
    if (n >= N_NODES) return;
    int d = min(counts[n], NDEG - 1);
    drank[n] = atomicAdd(&degHist[d], 1);
}

__global__ void lgcn_degscan(int* __restrict__ degHist) {
    int t = threadIdx.x;               // 64 threads = 1 wave
    int orig = degHist[t];
    int v = orig;
    for (int off = 1; off < NDEG; off <<= 1) {
        int u = __shfl_up(v, off);
        if (t >= off) v += u;
    }
    degHist[t] = v - orig;             // exclusive
}

__global__ void lgcn_order(const int* __restrict__ counts,
                           const int* __restrict__ drank,
                           const int* __restrict__ degHist,
                           int* __restrict__ order) {
    int n = blockIdx.x * blockDim.x + threadIdx.x;
    if (n >= N_NODES) return;
    int d = min(counts[n], NDEG - 1);
    order[degHist[d] + drank[n]] = n;
}

// ---------------------------------------------------------------------------
// pos precompute: one pass so the 8 binned passes only re-read pos (4.8MB)
// ---------------------------------------------------------------------------
__global__ void lgcn_pos(const int* __restrict__ dst,
                         const int* __restrict__ rank,
                         const int* __restrict__ rowptr,
                         int* __restrict__ pos) {
    int e = blockIdx.x * blockDim.x + threadIdx.x;
    if (e >= N_EDGES) return;
    pos[e] = rowptr[dst[e]] + rank[e];
}

// ---------------------------------------------------------------------------
// XCD-private binned CSR build (R7 known-good, no nt): block b handles edge
// chunk (b>>3), position-bin (b&7). blockIdx%8 -> XCD, so each bin's csr
// lines are dirtied by one XCD's L2 and mostly evict full.
// ---------------------------------------------------------------------------
__global__ void lgcn_csr_bin(const int*   __restrict__ src,
                             const float* __restrict__ vals,
                             const int*   __restrict__ pos,
                             uint2*       __restrict__ csr) {
    int b    = blockIdx.x;
    int bin  = b & (NBIN - 1);
    int e    = (b >> 3) * blockDim.x + threadIdx.x;
    if (e >= N_EDGES) return;
    int p  = pos[e];
    int lo = bin * BINSZ;
    if (p >= lo && p < lo + BINSZ) {
        csr[p] = make_uint2((unsigned)src[e], __float_as_uint(vals[e]));
    }
}

// ---------------------------------------------------------------------------
// ego row lookup: concat(user,item,brand) without materializing the concat
// ---------------------------------------------------------------------------
__device__ __forceinline__ const float4* ego_row(const float* __restrict__ user,
                                                 const float* __restrict__ item,
                                                 const float* __restrict__ brand,
                                                 int r) {
    if (r < NUM_USERS)
        return reinterpret_cast<const float4*>(user) + (r << 4);
    else if (r < NUM_USERS + NUM_ITEMS)
        return reinterpret_cast<const float4*>(item) + ((r - NUM_USERS) << 4);
    else
        return reinterpret_cast<const float4*>(brand) + ((r - NUM_USERS - NUM_ITEMS) << 4);
}

// row load, 8 floats per lane (8 lanes per row).
// LAYER 1: fp32 ego row (2x float4). LAYER 2/3: bf16 h row (1x uint4).
template <int LAYER>
__device__ __forceinline__ void load8(const float* __restrict__ user,
                                      const float* __restrict__ item,
                                      const float* __restrict__ brand,
                                      const uint4* __restrict__ h_src,
                                      int r, int q, float4& a, float4& b) {
    if (LAYER == 1) {
        const float4* er = ego_row(user, item, brand, r);
        a = er[2 * q];
        b = er[2 * q + 1];
    } else {
        uint4 w = h_src[(r << 3) + q];
        a = make_float4(bf_lo(w.x), bf_hi(w.x), bf_lo(w.y), bf_hi(w.y));
        b = make_float4(bf_lo(w.z), bf_hi(w.z), bf_lo(w.w), bf_hi(w.w));
    }
}

// ---------------------------------------------------------------------------
// gather SpMM, degree-ordered: node = order[slot] so the 8 node-groups in a
// wave have ~equal degree -> no masked max-degree tail (E[max of 8] ~ 8 vs
// E[deg] = 4 before). h writes are contiguous 128B full lines (no amp).
// 2-deep pipeline. LAYER=1: ego(fp32)->h1(bf16). LAYER=2: h1->h2.
// LAYER=3: h2 -> fused out = (ego + h1 + h2 + sum) * 0.25.
// ---------------------------------------------------------------------------
template <int LAYER>
__global__ void lgcn_gather(const int*   __restrict__ order,
                            const int*   __restrict__ rowptr,
                            const uint2* __restrict__ csr,
                            const float* __restrict__ user,
                            const float* __restrict__ item,
                            const float* __restrict__ brand,
                            const uint4* __restrict__ h1,
                            const uint4* __restrict__ h2,
                            uint4*       __restrict__ h_out,
                            float*       __restrict__ out) {
    int g    = blockIdx.x * blockDim.x + threadIdx.x;   // slot*8 + q
    int slot = g >> 3;
    int q    = g & 7;
    int node = order[slot];
    int beg = rowptr[node];
    int end = rowptr[node + 1];
    const uint4* h_src = (LAYER == 2) ? h1 : h2;        // LAYER 1 ignores this
    float4 s0 = make_float4(0.f, 0.f, 0.f, 0.f);
    float4 s1 = make_float4(0.f, 0.f, 0.f, 0.f);
    if (beg < end) {
        uint2 rec0 = csr[beg];
        uint2 rec1 = csr[(beg + 1 < end) ? beg + 1 : beg];
        float4 a0, b0;
        load8<LAYER>(user, item, brand, h_src, (int)rec0.x, q, a0, b0);
        for (int j = beg; j < end; ++j) {
            int jn = j + 2 < end ? j + 2 : end - 1;
            uint2 rec2 = csr[jn];                       // prefetch rec, 2 ahead
            float4 a1, b1;
            load8<LAYER>(user, item, brand, h_src, (int)rec1.x, q, a1, b1);
            float v = __uint_as_float(rec0.y);
            s0.x = fmaf(a0.x, v, s0.x);
            s0.y = fmaf(a0.y, v, s0.y);
            s0.z = fmaf(a0.z, v, s0.z);
            s0.w = fmaf(a0.w, v, s0.w);
            s1.x = fmaf(b0.x, v, s1.x);
            s1.y = fmaf(b0.y, v, s1.y);
            s1.z = fmaf(b0.z, v, s1.z);
            s1.w = fmaf(b0.w, v, s1.w);
            rec0 = rec1; rec1 = rec2; a0 = a1; b0 = b1;
        }
    }
    int hi = (node << 3) + q;                           // h row slot (uint4)
    if (LAYER != 3) {
        uint4 w;
        w.x = pack_bf(s0.x, s0.y);
        w.y = pack_bf(s0.z, s0.w);
        w.z = pack_bf(s1.x, s1.y);
        w.w = pack_bf(s1.z, s1.w);
        h_out[hi] = w;
    } else if (node < OUT_ROWS) {
        const float4* er = ego_row(user, item, brand, node);
        float4 e0 = er[2 * q];
        float4 e1 = er[2 * q + 1];
        uint4 w1 = h1[hi];
        uint4 w2 = h2[hi];
        float4 o0, o1;
        o0.x = (e0.x + bf_lo(w1.x) + bf_lo(w2.x) + s0.x) * 0.25f;
        o0.y = (e0.y + bf_hi(w1.x) + bf_hi(w2.x) + s0.y) * 0.25f;
        o0.z = (e0.z + bf_lo(w1.y) + bf_lo(w2.y) + s0.z) * 0.25f;
        o0.w = (e0.w + bf_hi(w1.y) + bf_hi(w2.y) + s0.w) * 0.25f;
        o1.x = (e1.x + bf_lo(w1.z) + bf_lo(w2.z) + s1.x) * 0.25f;
        o1.y = (e1.y + bf_hi(w1.z) + bf_hi(w2.z) + s1.y) * 0.25f;
        o1.z = (e1.z + bf_lo(w1.w) + bf_lo(w2.w) + s1.z) * 0.25f;
        o1.w = (e1.w + bf_hi(w1.w) + bf_hi(w2.w) + s1.w) * 0.25f;
        float4* o = reinterpret_cast<float4*>(out) + ((node << 3) + q) * 2;
        o[0] = o0;
        o[1] = o1;
    }
}

extern "C" void kernel_launch(void* const* d_in, const int* in_sizes, int n_in,
                              void* d_out, int out_size, void* d_ws, size_t ws_size,
                              hipStream_t stream) {
    const float* user  = (const float*)d_in[0];
    const float* item  = (const float*)d_in[1];
    const float* brand = (const float*)d_in[2];
    const float* vals  = (const float*)d_in[3];
    const int*   src   = (const int*)d_in[4];
    const int*   dst   = (const int*)d_in[5];
    float* out = (float*)d_out;

    // workspace layout (32-bit words); 16B alignment holds for uint4 arrays
    size_t W = 0;
    uint4* h1  = (uint4*)d_ws;                 W += (size_t)N_NODES * 32;   // bf16 rows (128B)
    uint4* h2  = (uint4*)((int*)d_ws + W);     W += (size_t)N_NODES * 32;
    uint2* csr = (uint2*)((int*)d_ws + W);     W += (size_t)N_EDGES * 2;
    int* rank      = (int*)d_ws + W;           W += N_EDGES;
    int* pos       = (int*)d_ws + W;           W += N_EDGES;
    int* rowptr    = (int*)d_ws + W;           W += N_NODES + 2;
    int* counts    = (int*)d_ws + W;           W += N_NODES;       // memset
    int* degHist   = (int*)d_ws + W;           W += 128;           // memset
    int* drank     = (int*)d_ws + W;           W += N_NODES;
    int* order     = (int*)d_ws + W;           W += N_NODES;
    int* blockSums = (int*)d_ws + W;           W += 512;
    (void)ws_size; (void)n_in; (void)in_sizes; (void)out_size;

    const int edgeBlocks   = (N_EDGES + 255) / 256;     // 4688
    const int nodeBlocks   = (N_NODES + 255) / 256;     // 1172
    const int gatherBlocks = (N_NODES * 8) / 256;       // 9375 (8 thr/node)

    // zero degree counters + degree histogram (adjacent -> one memset)
    hipMemsetAsync(counts, 0, (size_t)(N_NODES + 128) * sizeof(int), stream);

    // build dst-sorted CSR + degree-sorted processing order
    lgcn_hist   <<<edgeBlocks, 256, 0, stream>>>(dst, counts, rank);
    lgcn_scan_p1<<<NB, 256, 0, stream>>>(counts, rowptr, blockSums);
    lgcn_scan_p2<<<1, 512, 0, stream>>>(blockSums);
    lgcn_scan_p3<<<NB, 256, 0, stream>>>(rowptr, blockSums);
    lgcn_degbin <<<nodeBlocks, 256, 0, stream>>>(counts, degHist, drank);
    lgcn_degscan<<<1, NDEG, 0, stream>>>(degHist);
    lgcn_order  <<<nodeBlocks, 256, 0, stream>>>(counts, drank, degHist, order);
    lgcn_pos    <<<edgeBlocks, 256, 0, stream>>>(dst, rank, rowptr, pos);
    lgcn_csr_bin<<<NBIN * edgeBlocks, 256, 0, stream>>>(src, vals, pos, csr);

    // 3 atomic-free SpMM layers (bf16 intermediates, degree-ordered waves);
    // residual fused into layer 3
    lgcn_gather<1><<<gatherBlocks, 256, 0, stream>>>(order, rowptr, csr, user, item,
                                                     brand, h1, h2, h1, out);
    lgcn_gather<2><<<gatherBlocks, 256, 0, stream>>>(order, rowptr, csr, user, item,
                                                     brand, h1, h2, h2, out);
    lgcn_gather<3><<<gatherBlocks, 256, 0, stream>>>(order, rowptr, csr, user, item,
                                                     brand, h1, h2, nullptr, out);
}

// Round 11
// 278.794 us; speedup vs baseline: 5.3147x; 5.3147x over previous
//
#include <hip/hip_runtime.h>

#define NUM_USERS  150000
#define NUM_ITEMS  140000
#define NUM_BRANDS 10000
#define N_NODES    300000
#define DIM        64
#define N_EDGES    1200000
#define OUT_ROWS   290000          // users + items

#define CHUNK      1024            // elements per scan block
#define NB         ((N_NODES + CHUNK - 1) / CHUNK)   // 293 scan blocks

#define NBIN       8               // one bin per XCD
#define BINSZ      (N_EDGES / NBIN)                  // 150000 csr records/bin
#define NDEG       64              // degree buckets for counting sort

// ---------------------------------------------------------------------------
// bf16 helpers (h1/h2 stored as packed bf16: 64 dims = 8 uint4 per row)
// ---------------------------------------------------------------------------
__device__ __forceinline__ float bf_lo(unsigned u) { return __uint_as_float(u << 16); }
__device__ __forceinline__ float bf_hi(unsigned u) { return __uint_as_float(u & 0xffff0000u); }
__device__ __forceinline__ unsigned pack_bf(float a, float b) {
    unsigned ua = __float_as_uint(a); ua += 0x7fffu + ((ua >> 16) & 1u);
    unsigned ub = __float_as_uint(b); ub += 0x7fffu + ((ub >> 16) & 1u);
    return (ua >> 16) | (ub & 0xffff0000u);
}

// ---------------------------------------------------------------------------
// histogram of destination degrees + per-edge rank within its row
// ---------------------------------------------------------------------------
__global__ void lgcn_hist(const int* __restrict__ dst,
                          int* __restrict__ counts,
                          int* __restrict__ rank) {
    int e = blockIdx.x * blockDim.x + threadIdx.x;
    if (e >= N_EDGES) return;
    rank[e] = atomicAdd(&counts[dst[e]], 1);
}

// ---------------------------------------------------------------------------
// scan phase 1: per-1024-chunk exclusive scan (256 thr x 4 elem), chunk sums
// ---------------------------------------------------------------------------
__global__ void lgcn_scan_p1(const int* __restrict__ counts,
                             int* __restrict__ rowptr,
                             int* __restrict__ blockSums) {
    __shared__ int ts[256];
    int b    = blockIdx.x;
    int base = b * CHUNK;
    int t    = threadIdx.x;
    int c[4];
    int s = 0;
#pragma unroll
    for (int i = 0; i < 4; ++i) {
        int g = base + t * 4 + i;
        c[i] = (g < N_NODES) ? counts[g] : 0;
        s += c[i];
    }
    ts[t] = s;
    __syncthreads();
    for (int off = 1; off < 256; off <<= 1) {
        int v = (t >= off) ? ts[t - off] : 0;
        __syncthreads();
        ts[t] += v;
        __syncthreads();
    }
    int run = ts[t] - s;     // exclusive prefix of this thread's 4-group
#pragma unroll
    for (int i = 0; i < 4; ++i) {
        int g = base + t * 4 + i;
        if (g < N_NODES) rowptr[g] = run;
        run += c[i];
    }
    if (t == 255) blockSums[b] = ts[255];
}

// ---------------------------------------------------------------------------
// scan phase 2: single block exclusive-scans the NB (=293) chunk sums
// ---------------------------------------------------------------------------
__global__ void lgcn_scan_p2(int* __restrict__ blockSums) {
    __shared__ int sh[512];
    int t = threadIdx.x;
    int v = (t < NB) ? blockSums[t] : 0;
    sh[t] = v;
    __syncthreads();
    for (int off = 1; off < 512; off <<= 1) {
        int u = (t >= off) ? sh[t - off] : 0;
        __syncthreads();
        sh[t] += u;
        __syncthreads();
    }
    if (t < NB) blockSums[t] = sh[t] - v;   // exclusive
}

// ---------------------------------------------------------------------------
// scan phase 3: add chunk offsets; rowptr[N_NODES] = N_EDGES
// ---------------------------------------------------------------------------
__global__ void lgcn_scan_p3(int* __restrict__ rowptr,
                             const int* __restrict__ blockSums) {
    int b    = blockIdx.x;
    int base = b * CHUNK;
    int t    = threadIdx.x;
    int off  = blockSums[b];
#pragma unroll
    for (int i = 0; i < 4; ++i) {
        int g = base + t * 4 + i;
        if (g < N_NODES) rowptr[g] += off;
    }
    if (b == 0 && t == 0) rowptr[N_NODES] = N_EDGES;
}

// ---------------------------------------------------------------------------
// degree counting sort. R10 lesson: 300k global atomics on 64 counters =
// same-address serialization (1208us!). Hierarchical fix: LDS histogram per
// block, ONE global atomic per bucket per block, drank = blockBase + lds rank.
// ---------------------------------------------------------------------------
__global__ void lgcn_degbin(const int* __restrict__ counts,
                            int* __restrict__ degHist,
                            int* __restrict__ drank) {
    __shared__ int cnt[NDEG];
    __shared__ int base[NDEG];
    int t = threadIdx.x;
    int n = blockIdx.x * blockDim.x + t;
    if (t < NDEG) cnt[t] = 0;
    __syncthreads();
    int d = 0, lr = 0;
    bool valid = (n < N_NODES);
    if (valid) {
        d  = min(counts[n], NDEG - 1);
        lr = atomicAdd(&cnt[d], 1);            // LDS atomic: fast
    }
    __syncthreads();
    if (t < NDEG && cnt[t] > 0) base[t] = atomicAdd(&degHist[t], cnt[t]);
    __syncthreads();
    if (valid) drank[n] = base[d] + lr;
}

__global__ void lgcn_degscan(int* __restrict__ degHist) {
    int t = threadIdx.x;               // 64 threads = 1 wave
    int orig = degHist[t];
    int v = orig;
    for (int off = 1; off < NDEG; off <<= 1) {
        int u = __shfl_up(v, off);
        if (t >= off) v += u;
    }
    degHist[t] = v - orig;             // exclusive
}

__global__ void lgcn_order(const int* __restrict__ counts,
                           const int* __restrict__ drank,
                           const int* __restrict__ degHist,
                           int* __restrict__ order) {
    int n = blockIdx.x * blockDim.x + threadIdx.x;
    if (n >= N_NODES) return;
    int d = min(counts[n], NDEG - 1);
    order[degHist[d] + drank[n]] = n;
}

// ---------------------------------------------------------------------------
// pos precompute: one pass so the 8 binned passes only re-read pos (4.8MB)
// ---------------------------------------------------------------------------
__global__ void lgcn_pos(const int* __restrict__ dst,
                         const int* __restrict__ rank,
                         const int* __restrict__ rowptr,
                         int* __restrict__ pos) {
    int e = blockIdx.x * blockDim.x + threadIdx.x;
    if (e >= N_EDGES) return;
    pos[e] = rowptr[dst[e]] + rank[e];
}

// ---------------------------------------------------------------------------
// XCD-private binned CSR build (R7 known-good, no nt): block b handles edge
// chunk (b>>3), position-bin (b&7). blockIdx%8 -> XCD, so each bin's csr
// lines are dirtied by one XCD's L2 and mostly evict full.
// ---------------------------------------------------------------------------
__global__ void lgcn_csr_bin(const int*   __restrict__ src,
                             const float* __restrict__ vals,
                             const int*   __restrict__ pos,
                             uint2*       __restrict__ csr) {
    int b    = blockIdx.x;
    int bin  = b & (NBIN - 1);
    int e    = (b >> 3) * blockDim.x + threadIdx.x;
    if (e >= N_EDGES) return;
    int p  = pos[e];
    int lo = bin * BINSZ;
    if (p >= lo && p < lo + BINSZ) {
        csr[p] = make_uint2((unsigned)src[e], __float_as_uint(vals[e]));
    }
}

// ---------------------------------------------------------------------------
// ego row lookup: concat(user,item,brand) without materializing the concat
// ---------------------------------------------------------------------------
__device__ __forceinline__ const float4* ego_row(const float* __restrict__ user,
                                                 const float* __restrict__ item,
                                                 const float* __restrict__ brand,
                                                 int r) {
    if (r < NUM_USERS)
        return reinterpret_cast<const float4*>(user) + (r << 4);
    else if (r < NUM_USERS + NUM_ITEMS)
        return reinterpret_cast<const float4*>(item) + ((r - NUM_USERS) << 4);
    else
        return reinterpret_cast<const float4*>(brand) + ((r - NUM_USERS - NUM_ITEMS) << 4);
}

// row load, 8 floats per lane (8 lanes per row).
// LAYER 1: fp32 ego row (2x float4). LAYER 2/3: bf16 h row (1x uint4).
template <int LAYER>
__device__ __forceinline__ void load8(const float* __restrict__ user,
                                      const float* __restrict__ item,
                                      const float* __restrict__ brand,
                                      const uint4* __restrict__ h_src,
                                      int r, int q, float4& a, float4& b) {
    if (LAYER == 1) {
        const float4* er = ego_row(user, item, brand, r);
        a = er[2 * q];
        b = er[2 * q + 1];
    } else {
        uint4 w = h_src[(r << 3) + q];
        a = make_float4(bf_lo(w.x), bf_hi(w.x), bf_lo(w.y), bf_hi(w.y));
        b = make_float4(bf_lo(w.z), bf_hi(w.z), bf_lo(w.w), bf_hi(w.w));
    }
}

// ---------------------------------------------------------------------------
// gather SpMM, degree-ordered: node = order[slot] so the 8 node-groups in a
// wave have ~equal degree -> no masked max-degree tail. h writes are
// contiguous 128B full lines. 2-deep pipeline.
// LAYER=1: ego(fp32)->h1(bf16). LAYER=2: h1->h2. LAYER=3: h2 -> fused
// out = (ego + h1 + h2 + sum) * 0.25.
// ---------------------------------------------------------------------------
template <int LAYER>
__global__ void lgcn_gather(const int*   __restrict__ order,
                            const int*   __restrict__ rowptr,
                            const uint2* __restrict__ csr,
                            const float* __restrict__ user,
                            const float* __restrict__ item,
                            const float* __restrict__ brand,
                            const uint4* __restrict__ h1,
                            const uint4* __restrict__ h2,
                            uint4*       __restrict__ h_out,
                            float*       __restrict__ out) {
    int g    = blockIdx.x * blockDim.x + threadIdx.x;   // slot*8 + q
    int slot = g >> 3;
    int q    = g & 7;
    int node = order[slot];
    int beg = rowptr[node];
    int end = rowptr[node + 1];
    const uint4* h_src = (LAYER == 2) ? h1 : h2;        // LAYER 1 ignores this
    float4 s0 = make_float4(0.f, 0.f, 0.f, 0.f);
    float4 s1 = make_float4(0.f, 0.f, 0.f, 0.f);
    if (beg < end) {
        uint2 rec0 = csr[beg];
        uint2 rec1 = csr[(beg + 1 < end) ? beg + 1 : beg];
        float4 a0, b0;
        load8<LAYER>(user, item, brand, h_src, (int)rec0.x, q, a0, b0);
        for (int j = beg; j < end; ++j) {
            int jn = j + 2 < end ? j + 2 : end - 1;
            uint2 rec2 = csr[jn];                       // prefetch rec, 2 ahead
            float4 a1, b1;
            load8<LAYER>(user, item, brand, h_src, (int)rec1.x, q, a1, b1);
            float v = __uint_as_float(rec0.y);
            s0.x = fmaf(a0.x, v, s0.x);
            s0.y = fmaf(a0.y, v, s0.y);
            s0.z = fmaf(a0.z, v, s0.z);
            s0.w = fmaf(a0.w, v, s0.w);
            s1.x = fmaf(b0.x, v, s1.x);
            s1.y = fmaf(b0.y, v, s1.y);
            s1.z = fmaf(b0.z, v, s1.z);
            s1.w = fmaf(b0.w, v, s1.w);
            rec0 = rec1; rec1 = rec2; a0 = a1; b0 = b1;
        }
    }
    int hi = (node << 3) + q;                           // h row slot (uint4)
    if (LAYER != 3) {
        uint4 w;
        w.x = pack_bf(s0.x, s0.y);
        w.y = pack_bf(s0.z, s0.w);
        w.z = pack_bf(s1.x, s1.y);
        w.w = pack_bf(s1.z, s1.w);
        h_out[hi] = w;
    } else if (node < OUT_ROWS) {
        const float4* er = ego_row(user, item, brand, node);
        float4 e0 = er[2 * q];
        float4 e1 = er[2 * q + 1];
        uint4 w1 = h1[hi];
        uint4 w2 = h2[hi];
        float4 o0, o1;
        o0.x = (e0.x + bf_lo(w1.x) + bf_lo(w2.x) + s0.x) * 0.25f;
        o0.y = (e0.y + bf_hi(w1.x) + bf_hi(w2.x) + s0.y) * 0.25f;
        o0.z = (e0.z + bf_lo(w1.y) + bf_lo(w2.y) + s0.z) * 0.25f;
        o0.w = (e0.w + bf_hi(w1.y) + bf_hi(w2.y) + s0.w) * 0.25f;
        o1.x = (e1.x + bf_lo(w1.z) + bf_lo(w2.z) + s1.x) * 0.25f;
        o1.y = (e1.y + bf_hi(w1.z) + bf_hi(w2.z) + s1.y) * 0.25f;
        o1.z = (e1.z + bf_lo(w1.w) + bf_lo(w2.w) + s1.z) * 0.25f;
        o1.w = (e1.w + bf_hi(w1.w) + bf_hi(w2.w) + s1.w) * 0.25f;
        float4* o = reinterpret_cast<float4*>(out) + ((node << 3) + q) * 2;
        o[0] = o0;
        o[1] = o1;
    }
}

extern "C" void kernel_launch(void* const* d_in, const int* in_sizes, int n_in,
                              void* d_out, int out_size, void* d_ws, size_t ws_size,
                              hipStream_t stream) {
    const float* user  = (const float*)d_in[0];
    const float* item  = (const float*)d_in[1];
    const float* brand = (const float*)d_in[2];
    const float* vals  = (const float*)d_in[3];
    const int*   src   = (const int*)d_in[4];
    const int*   dst   = (const int*)d_in[5];
    float* out = (float*)d_out;

    // workspace layout (32-bit words); 16B alignment holds for uint4 arrays
    size_t W = 0;
    uint4* h1  = (uint4*)d_ws;                 W += (size_t)N_NODES * 32;   // bf16 rows (128B)
    uint4* h2  = (uint4*)((int*)d_ws + W);     W += (size_t)N_NODES * 32;
    uint2* csr = (uint2*)((int*)d_ws + W);     W += (size_t)N_EDGES * 2;
    int* rank      = (int*)d_ws + W;           W += N_EDGES;
    int* pos       = (int*)d_ws + W;           W += N_EDGES;
    int* rowptr    = (int*)d_ws + W;           W += N_NODES + 2;
    int* counts    = (int*)d_ws + W;           W += N_NODES;       // memset
    int* degHist   = (int*)d_ws + W;           W += 128;           // memset
    int* drank     = (int*)d_ws + W;           W += N_NODES;
    int* order     = (int*)d_ws + W;           W += N_NODES;
    int* blockSums = (int*)d_ws + W;           W += 512;
    (void)ws_size; (void)n_in; (void)in_sizes; (void)out_size;

    const int edgeBlocks   = (N_EDGES + 255) / 256;     // 4688
    const int nodeBlocks   = (N_NODES + 255) / 256;     // 1172
    const int gatherBlocks = (N_NODES * 8) / 256;       // 9375 (8 thr/node)

    // zero degree counters + degree histogram (adjacent -> one memset)
    hipMemsetAsync(counts, 0, (size_t)(N_NODES + 128) * sizeof(int), stream);

    // build dst-sorted CSR + degree-sorted processing order
    lgcn_hist   <<<edgeBlocks, 256, 0, stream>>>(dst, counts, rank);
    lgcn_scan_p1<<<NB, 256, 0, stream>>>(counts, rowptr, blockSums);
    lgcn_scan_p2<<<1, 512, 0, stream>>>(blockSums);
    lgcn_scan_p3<<<NB, 256, 0, stream>>>(rowptr, blockSums);
    lgcn_degbin <<<nodeBlocks, 256, 0, stream>>>(counts, degHist, drank);
    lgcn_degscan<<<1, NDEG, 0, stream>>>(degHist);
    lgcn_order  <<<nodeBlocks, 256, 0, stream>>>(counts, drank, degHist, order);
    lgcn_pos    <<<edgeBlocks, 256, 0, stream>>>(dst, rank, rowptr, pos);
    lgcn_csr_bin<<<NBIN * edgeBlocks, 256, 0, stream>>>(src, vals, pos, csr);

    // 3 atomic-free SpMM layers (bf16 intermediates, degree-ordered waves);
    // residual fused into layer 3
    lgcn_gather<1><<<gatherBlocks, 256, 0, stream>>>(order, rowptr, csr, user, item,
                                                     brand, h1, h2, h1, out);
    lgcn_gather<2><<<gatherBlocks, 256, 0, stream>>>(order, rowptr, csr, user, item,
                                                     brand, h1, h2, h2, out);
    lgcn_gather<3><<<gatherBlocks, 256, 0, stream>>>(order, rowptr, csr, user, item,
                                                     brand, h1, h2, nullptr, out);
}

// Round 12
// 273.721 us; speedup vs baseline: 5.4132x; 1.0185x over previous
//
#include <hip/hip_runtime.h>

#define NUM_USERS  150000
#define NUM_ITEMS  140000
#define NUM_BRANDS 10000
#define N_NODES    300000
#define DIM        64
#define N_EDGES    1200000
#define OUT_ROWS   290000          // users + items

#define CHUNK      1024            // elements per scan block
#define NB         ((N_NODES + CHUNK - 1) / CHUNK)   // 293 scan blocks

#define NBIN       8               // one bin per XCD
#define BINSZ      (N_EDGES / NBIN)                  // 150000 csr records/bin

// ---------------------------------------------------------------------------
// bf16 helpers (ego/h1/h2 stored as packed bf16: 64 dims = 8 uint4 per row)
// ---------------------------------------------------------------------------
__device__ __forceinline__ float bf_lo(unsigned u) { return __uint_as_float(u << 16); }
__device__ __forceinline__ float bf_hi(unsigned u) { return __uint_as_float(u & 0xffff0000u); }
__device__ __forceinline__ unsigned pack_bf(float a, float b) {
    unsigned ua = __float_as_uint(a); ua += 0x7fffu + ((ua >> 16) & 1u);
    unsigned ub = __float_as_uint(b); ub += 0x7fffu + ((ub >> 16) & 1u);
    return (ua >> 16) | (ub & 0xffff0000u);
}

// ---------------------------------------------------------------------------
// histogram of destination degrees + per-edge rank within its row
// ---------------------------------------------------------------------------
__global__ void lgcn_hist(const int* __restrict__ dst,
                          int* __restrict__ counts,
                          int* __restrict__ rank) {
    int e = blockIdx.x * blockDim.x + threadIdx.x;
    if (e >= N_EDGES) return;
    rank[e] = atomicAdd(&counts[dst[e]], 1);
}

// ---------------------------------------------------------------------------
// scan phase 1: per-1024-chunk exclusive scan (256 thr x 4 elem), chunk sums
// ---------------------------------------------------------------------------
__global__ void lgcn_scan_p1(const int* __restrict__ counts,
                             int* __restrict__ rowptr,
                             int* __restrict__ blockSums) {
    __shared__ int ts[256];
    int b    = blockIdx.x;
    int base = b * CHUNK;
    int t    = threadIdx.x;
    int c[4];
    int s = 0;
#pragma unroll
    for (int i = 0; i < 4; ++i) {
        int g = base + t * 4 + i;
        c[i] = (g < N_NODES) ? counts[g] : 0;
        s += c[i];
    }
    ts[t] = s;
    __syncthreads();
    for (int off = 1; off < 256; off <<= 1) {
        int v = (t >= off) ? ts[t - off] : 0;
        __syncthreads();
        ts[t] += v;
        __syncthreads();
    }
    int run = ts[t] - s;     // exclusive prefix of this thread's 4-group
#pragma unroll
    for (int i = 0; i < 4; ++i) {
        int g = base + t * 4 + i;
        if (g < N_NODES) rowptr[g] = run;
        run += c[i];
    }
    if (t == 255) blockSums[b] = ts[255];
}

// ---------------------------------------------------------------------------
// scan phase 2: single block exclusive-scans the NB (=293) chunk sums
// ---------------------------------------------------------------------------
__global__ void lgcn_scan_p2(int* __restrict__ blockSums) {
    __shared__ int sh[512];
    int t = threadIdx.x;
    int v = (t < NB) ? blockSums[t] : 0;
    sh[t] = v;
    __syncthreads();
    for (int off = 1; off < 512; off <<= 1) {
        int u = (t >= off) ? sh[t - off] : 0;
        __syncthreads();
        sh[t] += u;
        __syncthreads();
    }
    if (t < NB) blockSums[t] = sh[t] - v;   // exclusive
}

// ---------------------------------------------------------------------------
// scan phase 3: add chunk offsets; rowptr[N_NODES] = N_EDGES
// ---------------------------------------------------------------------------
__global__ void lgcn_scan_p3(int* __restrict__ rowptr,
                             const int* __restrict__ blockSums) {
    int b    = blockIdx.x;
    int base = b * CHUNK;
    int t    = threadIdx.x;
    int off  = blockSums[b];
#pragma unroll
    for (int i = 0; i < 4; ++i) {
        int g = base + t * 4 + i;
        if (g < N_NODES) rowptr[g] += off;
    }
    if (b == 0 && t == 0) rowptr[N_NODES] = N_EDGES;
}

// ---------------------------------------------------------------------------
// ego -> bf16 copy: one streaming pass; 8 lanes per row, lane reads 2 fp32
// float4 (32B) and writes 1 uint4 (16B). Makes all 3 gathers read 128B rows.
// ---------------------------------------------------------------------------
__global__ void lgcn_egobf(const float* __restrict__ user,
                           const float* __restrict__ item,
                           const float* __restrict__ brand,
                           uint4* __restrict__ ego_bf) {
    int g = blockIdx.x * blockDim.x + threadIdx.x;      // row*8 + q
    if (g >= N_NODES * 8) return;
    int row = g >> 3;
    int q   = g & 7;
    const float* srcp;
    if (row < NUM_USERS)                    srcp = user  + ((size_t)row << 6);
    else if (row < NUM_USERS + NUM_ITEMS)   srcp = item  + ((size_t)(row - NUM_USERS) << 6);
    else                                    srcp = brand + ((size_t)(row - NUM_USERS - NUM_ITEMS) << 6);
    float4 e0 = *(reinterpret_cast<const float4*>(srcp) + 2 * q);
    float4 e1 = *(reinterpret_cast<const float4*>(srcp) + 2 * q + 1);
    uint4 w;
    w.x = pack_bf(e0.x, e0.y);
    w.y = pack_bf(e0.z, e0.w);
    w.z = pack_bf(e1.x, e1.y);
    w.w = pack_bf(e1.z, e1.w);
    ego_bf[g] = w;
}

// ---------------------------------------------------------------------------
// XCD-private binned CSR build (R7 known-good): block b handles edge chunk
// (b>>3), position-bin (b&7). blockIdx%8 -> XCD, so each bin's csr lines are
// dirtied by one XCD's L2 and mostly evict full.
// ---------------------------------------------------------------------------
__global__ void lgcn_csr_bin(const int*   __restrict__ src,
                             const int*   __restrict__ dst,
                             const float* __restrict__ vals,
                             const int*   __restrict__ rank,
                             const int*   __restrict__ rowptr,
                             uint2*       __restrict__ csr) {
    int b    = blockIdx.x;
    int bin  = b & (NBIN - 1);
    int e    = (b >> 3) * blockDim.x + threadIdx.x;
    if (e >= N_EDGES) return;
    int pos = rowptr[dst[e]] + rank[e];
    int lo  = bin * BINSZ;
    if (pos >= lo && pos < lo + BINSZ) {
        csr[pos] = make_uint2((unsigned)src[e], __float_as_uint(vals[e]));
    }
}

// ---------------------------------------------------------------------------
// fp32 ego row lookup (layer-3 epilogue only; sequential, full precision)
// ---------------------------------------------------------------------------
__device__ __forceinline__ const float4* ego_row(const float* __restrict__ user,
                                                 const float* __restrict__ item,
                                                 const float* __restrict__ brand,
                                                 int r) {
    if (r < NUM_USERS)
        return reinterpret_cast<const float4*>(user) + (r << 4);
    else if (r < NUM_USERS + NUM_ITEMS)
        return reinterpret_cast<const float4*>(item) + ((r - NUM_USERS) << 4);
    else
        return reinterpret_cast<const float4*>(brand) + ((r - NUM_USERS - NUM_ITEMS) << 4);
}

// ---------------------------------------------------------------------------
// gather SpMM: 8 lanes per dst node (8 dims/lane), 8 nodes per wave.
// 4-deep pipeline with RAW-WORD staging: prefetched rows stay as uint4 and
// are unpacked only at consume time, so the compiler's waitcnt covers the
// OLDEST outstanding load, keeping ~3 rows + 4 recs in flight per group
// (~2x the in-flight bytes of the 2-deep version; we measured the gathers
// concurrency-bound: 2.4-3.2 TB/s, VALUBusy 24%, no pipe saturated).
// All layers read bf16 rows (h_src); LAYER=3 fuses the residual epilogue
// out = (ego_fp32 + h1 + h2 + sum) * 0.25.
// ---------------------------------------------------------------------------
template <int LAYER>
__global__ void lgcn_gather(const int*   __restrict__ rowptr,
                            const uint2* __restrict__ csr,
                            const uint4* __restrict__ h_src,
                            const float* __restrict__ user,
                            const float* __restrict__ item,
                            const float* __restrict__ brand,
                            const uint4* __restrict__ h1,
                            const uint4* __restrict__ h2,
                            uint4*       __restrict__ h_out,
                            float*       __restrict__ out) {
    int g    = blockIdx.x * blockDim.x + threadIdx.x;   // node*8 + q
    int node = g >> 3;
    int q    = g & 7;
    int beg = rowptr[node];
    int end = rowptr[node + 1];
    float4 s0 = make_float4(0.f, 0.f, 0.f, 0.f);
    float4 s1 = make_float4(0.f, 0.f, 0.f, 0.f);
    if (beg < end) {
        int last = end - 1;
        uint2 rec0 = csr[beg];
        uint2 rec1 = csr[beg + 1 < end ? beg + 1 : last];
        uint2 rec2 = csr[beg + 2 < end ? beg + 2 : last];
        uint2 rec3 = csr[beg + 3 < end ? beg + 3 : last];
        uint4 w0 = h_src[((int)rec0.x << 3) + q];       // raw bf16 words
        uint4 w1 = h_src[((int)rec1.x << 3) + q];
        uint4 w2 = h_src[((int)rec2.x << 3) + q];
        for (int j = beg; j < end; ++j) {
            int jn = j + 4 < end ? j + 4 : last;
            uint2 rec4 = csr[jn];                       // rec, 4 ahead
            uint4 w3 = h_src[((int)rec3.x << 3) + q];   // row, 3 ahead (raw)
            float v = __uint_as_float(rec0.y);
            s0.x = fmaf(bf_lo(w0.x), v, s0.x);          // unpack at consume
            s0.y = fmaf(bf_hi(w0.x), v, s0.y);
            s0.z = fmaf(bf_lo(w0.y), v, s0.z);
            s0.w = fmaf(bf_hi(w0.y), v, s0.w);
            s1.x = fmaf(bf_lo(w0.z), v, s1.x);
            s1.y = fmaf(bf_hi(w0.z), v, s1.y);
            s1.z = fmaf(bf_lo(w0.w), v, s1.z);
            s1.w = fmaf(bf_hi(w0.w), v, s1.w);
            rec0 = rec1; rec1 = rec2; rec2 = rec3; rec3 = rec4;
            w0 = w1; w1 = w2; w2 = w3;
        }
    }
    if (LAYER != 3) {
        uint4 w;
        w.x = pack_bf(s0.x, s0.y);
        w.y = pack_bf(s0.z, s0.w);
        w.z = pack_bf(s1.x, s1.y);
        w.w = pack_bf(s1.z, s1.w);
        h_out[g] = w;
    } else if (node < OUT_ROWS) {
        const float4* er = ego_row(user, item, brand, node);
        float4 e0 = er[2 * q];
        float4 e1 = er[2 * q + 1];
        uint4 w1 = h1[g];
        uint4 w2 = h2[g];
        float4 o0, o1;
        o0.x = (e0.x + bf_lo(w1.x) + bf_lo(w2.x) + s0.x) * 0.25f;
        o0.y = (e0.y + bf_hi(w1.x) + bf_hi(w2.x) + s0.y) * 0.25f;
        o0.z = (e0.z + bf_lo(w1.y) + bf_lo(w2.y) + s0.z) * 0.25f;
        o0.w = (e0.w + bf_hi(w1.y) + bf_hi(w2.y) + s0.w) * 0.25f;
        o1.x = (e1.x + bf_lo(w1.z) + bf_lo(w2.z) + s1.x) * 0.25f;
        o1.y = (e1.y + bf_hi(w1.z) + bf_hi(w2.z) + s1.y) * 0.25f;
        o1.z = (e1.z + bf_lo(w1.w) + bf_lo(w2.w) + s1.z) * 0.25f;
        o1.w = (e1.w + bf_hi(w1.w) + bf_hi(w2.w) + s1.w) * 0.25f;
        float4* o = reinterpret_cast<float4*>(out) + g * 2;
        o[0] = o0;
        o[1] = o1;
    }
}

extern "C" void kernel_launch(void* const* d_in, const int* in_sizes, int n_in,
                              void* d_out, int out_size, void* d_ws, size_t ws_size,
                              hipStream_t stream) {
    const float* user  = (const float*)d_in[0];
    const float* item  = (const float*)d_in[1];
    const float* brand = (const float*)d_in[2];
    const float* vals  = (const float*)d_in[3];
    const int*   src   = (const int*)d_in[4];
    const int*   dst   = (const int*)d_in[5];
    float* out = (float*)d_out;

    // workspace layout (32-bit words); 16B alignment holds for uint4 arrays
    size_t W = 0;
    uint4* ego_bf = (uint4*)d_ws;              W += (size_t)N_NODES * 32;   // bf16 rows (128B)
    uint4* h1  = (uint4*)((int*)d_ws + W);     W += (size_t)N_NODES * 32;
    uint4* h2  = (uint4*)((int*)d_ws + W);     W += (size_t)N_NODES * 32;
    uint2* csr = (uint2*)((int*)d_ws + W);     W += (size_t)N_EDGES * 2;
    int* rank      = (int*)d_ws + W;           W += N_EDGES;
    int* rowptr    = (int*)d_ws + W;           W += N_NODES + 2;
    int* counts    = (int*)d_ws + W;           W += N_NODES;       // memset
    int* blockSums = (int*)d_ws + W;           W += 512;
    (void)ws_size; (void)n_in; (void)in_sizes; (void)out_size;

    const int edgeBlocks   = (N_EDGES + 255) / 256;     // 4688
    const int gatherBlocks = (N_NODES * 8) / 256;       // 9375 (8 thr/node)

    // zero degree counters (workspace is poisoned; hist accumulates)
    hipMemsetAsync(counts, 0, (size_t)N_NODES * sizeof(int), stream);

    // ego -> bf16 rows (overlaps nothing; pure streaming)
    lgcn_egobf  <<<gatherBlocks, 256, 0, stream>>>(user, item, brand, ego_bf);

    // build dst-sorted CSR: hist+rank -> scan -> XCD-binned record scatter
    lgcn_hist   <<<edgeBlocks, 256, 0, stream>>>(dst, counts, rank);
    lgcn_scan_p1<<<NB, 256, 0, stream>>>(counts, rowptr, blockSums);
    lgcn_scan_p2<<<1, 512, 0, stream>>>(blockSums);
    lgcn_scan_p3<<<NB, 256, 0, stream>>>(rowptr, blockSums);
    lgcn_csr_bin<<<NBIN * edgeBlocks, 256, 0, stream>>>(src, dst, vals, rank,
                                                        rowptr, csr);

    // 3 atomic-free SpMM layers (bf16 rows everywhere); residual fused in L3
    lgcn_gather<1><<<gatherBlocks, 256, 0, stream>>>(rowptr, csr, ego_bf, user, item,
                                                     brand, h1, h2, h1, out);
    lgcn_gather<2><<<gatherBlocks, 256, 0, stream>>>(rowptr, csr, h1, user, item,
                                                     brand, h1, h2, h2, out);
    lgcn_gather<3><<<gatherBlocks, 256, 0, stream>>>(rowptr, csr, h2, user, item,
                                                     brand, h1, h2, nullptr, out);
}

// Round 13
// 240.977 us; speedup vs baseline: 6.1487x; 1.1359x over previous
//
#include <hip/hip_runtime.h>

#define NUM_USERS  150000
#define NUM_ITEMS  140000
#define NUM_BRANDS 10000
#define N_NODES    300000
#define DIM        64
#define N_EDGES    1200000
#define OUT_ROWS   290000          // users + items

#define CHUNK      1024            // elements per scan block
#define NB         ((N_NODES + CHUNK - 1) / CHUNK)   // 293 scan blocks

#define NBIN       8               // one bin per XCD
#define BINSZ      (N_EDGES / NBIN)                  // 150000 csr records/bin

// ---------------------------------------------------------------------------
// bf16 helpers (h1/h2 stored as packed bf16: 64 dims = 8 uint4 per row)
// ---------------------------------------------------------------------------
__device__ __forceinline__ float bf_lo(unsigned u) { return __uint_as_float(u << 16); }
__device__ __forceinline__ float bf_hi(unsigned u) { return __uint_as_float(u & 0xffff0000u); }
__device__ __forceinline__ unsigned pack_bf(float a, float b) {
    unsigned ua = __float_as_uint(a); ua += 0x7fffu + ((ua >> 16) & 1u);
    unsigned ub = __float_as_uint(b); ub += 0x7fffu + ((ub >> 16) & 1u);
    return (ua >> 16) | (ub & 0xffff0000u);
}

// ---------------------------------------------------------------------------
// histogram of destination degrees + per-edge rank within its row
// ---------------------------------------------------------------------------
__global__ void lgcn_hist(const int* __restrict__ dst,
                          int* __restrict__ counts,
                          int* __restrict__ rank) {
    int e = blockIdx.x * blockDim.x + threadIdx.x;
    if (e >= N_EDGES) return;
    rank[e] = atomicAdd(&counts[dst[e]], 1);
}

// ---------------------------------------------------------------------------
// scan phase 1: per-1024-chunk exclusive scan (256 thr x 4 elem), chunk sums
// ---------------------------------------------------------------------------
__global__ void lgcn_scan_p1(const int* __restrict__ counts,
                             int* __restrict__ rowptr,
                             int* __restrict__ blockSums) {
    __shared__ int ts[256];
    int b    = blockIdx.x;
    int base = b * CHUNK;
    int t    = threadIdx.x;
    int c[4];
    int s = 0;
#pragma unroll
    for (int i = 0; i < 4; ++i) {
        int g = base + t * 4 + i;
        c[i] = (g < N_NODES) ? counts[g] : 0;
        s += c[i];
    }
    ts[t] = s;
    __syncthreads();
    for (int off = 1; off < 256; off <<= 1) {
        int v = (t >= off) ? ts[t - off] : 0;
        __syncthreads();
        ts[t] += v;
        __syncthreads();
    }
    int run = ts[t] - s;     // exclusive prefix of this thread's 4-group
#pragma unroll
    for (int i = 0; i < 4; ++i) {
        int g = base + t * 4 + i;
        if (g < N_NODES) rowptr[g] = run;
        run += c[i];
    }
    if (t == 255) blockSums[b] = ts[255];
}

// ---------------------------------------------------------------------------
// scan phase 2: single block exclusive-scans the NB (=293) chunk sums
// ---------------------------------------------------------------------------
__global__ void lgcn_scan_p2(int* __restrict__ blockSums) {
    __shared__ int sh[512];
    int t = threadIdx.x;
    int v = (t < NB) ? blockSums[t] : 0;
    sh[t] = v;
    __syncthreads();
    for (int off = 1; off < 512; off <<= 1) {
        int u = (t >= off) ? sh[t - off] : 0;
        __syncthreads();
        sh[t] += u;
        __syncthreads();
    }
    if (t < NB) blockSums[t] = sh[t] - v;   // exclusive
}

// ---------------------------------------------------------------------------
// scan phase 3: add chunk offsets; rowptr[N_NODES] = N_EDGES
// ---------------------------------------------------------------------------
__global__ void lgcn_scan_p3(int* __restrict__ rowptr,
                             const int* __restrict__ blockSums) {
    int b    = blockIdx.x;
    int base = b * CHUNK;
    int t    = threadIdx.x;
    int off  = blockSums[b];
#pragma unroll
    for (int i = 0; i < 4; ++i) {
        int g = base + t * 4 + i;
        if (g < N_NODES) rowptr[g] += off;
    }
    if (b == 0 && t == 0) rowptr[N_NODES] = N_EDGES;
}

// ---------------------------------------------------------------------------
// pos precompute: one pass so the 8 binned passes re-read only pos (4.8MB)
// (R11 evidence: cuts csr_bin ~65 -> ~40us vs re-deriving pos each pass)
// ---------------------------------------------------------------------------
__global__ void lgcn_pos(const int* __restrict__ dst,
                         const int* __restrict__ rank,
                         const int* __restrict__ rowptr,
                         int* __restrict__ pos) {
    int e = blockIdx.x * blockDim.x + threadIdx.x;
    if (e >= N_EDGES) return;
    pos[e] = rowptr[dst[e]] + rank[e];
}

// ---------------------------------------------------------------------------
// XCD-private binned CSR build: block b handles edge chunk (b>>3), position
// bin (b&7). blockIdx%8 -> XCD, so each bin's csr lines are dirtied by one
// XCD's L2 and mostly evict full.
// ---------------------------------------------------------------------------
__global__ void lgcn_csr_bin(const int*   __restrict__ src,
                             const float* __restrict__ vals,
                             const int*   __restrict__ pos,
                             uint2*       __restrict__ csr) {
    int b    = blockIdx.x;
    int bin  = b & (NBIN - 1);
    int e    = (b >> 3) * blockDim.x + threadIdx.x;
    if (e >= N_EDGES) return;
    int p  = pos[e];
    int lo = bin * BINSZ;
    if (p >= lo && p < lo + BINSZ) {
        csr[p] = make_uint2((unsigned)src[e], __float_as_uint(vals[e]));
    }
}

// ---------------------------------------------------------------------------
// fp32 ego row lookup: concat(user,item,brand) without materializing it
// ---------------------------------------------------------------------------
__device__ __forceinline__ const float4* ego_row(const float* __restrict__ user,
                                                 const float* __restrict__ item,
                                                 const float* __restrict__ brand,
                                                 int r) {
    if (r < NUM_USERS)
        return reinterpret_cast<const float4*>(user) + (r << 4);
    else if (r < NUM_USERS + NUM_ITEMS)
        return reinterpret_cast<const float4*>(item) + ((r - NUM_USERS) << 4);
    else
        return reinterpret_cast<const float4*>(brand) + ((r - NUM_USERS - NUM_ITEMS) << 4);
}

// ---------------------------------------------------------------------------
// Row storage trait: LAYER 1 reads fp32 ego rows (2x float4 per lane);
// LAYER 2/3 read raw bf16 words (1x uint4 per lane), unpacked only at the
// fma (so the compiler's waitcnt tracks the oldest outstanding load).
// ---------------------------------------------------------------------------
template <int LAYER>
struct RowStore {
    typedef uint4 type;
    static __device__ __forceinline__ type load(const uint4* __restrict__ h,
                                                const float*, const float*, const float*,
                                                int r, int q) {
        return h[(r << 3) + q];
    }
    static __device__ __forceinline__ void fma(float4& s0, float4& s1, type w, float v) {
        s0.x = fmaf(bf_lo(w.x), v, s0.x);
        s0.y = fmaf(bf_hi(w.x), v, s0.y);
        s0.z = fmaf(bf_lo(w.y), v, s0.z);
        s0.w = fmaf(bf_hi(w.y), v, s0.w);
        s1.x = fmaf(bf_lo(w.z), v, s1.x);
        s1.y = fmaf(bf_hi(w.z), v, s1.y);
        s1.z = fmaf(bf_lo(w.w), v, s1.z);
        s1.w = fmaf(bf_hi(w.w), v, s1.w);
    }
};

struct Row8 { float4 a, b; };
template <>
struct RowStore<1> {
    typedef Row8 type;
    static __device__ __forceinline__ type load(const uint4*,
                                                const float* __restrict__ u,
                                                const float* __restrict__ i,
                                                const float* __restrict__ b,
                                                int r, int q) {
        const float4* er = ego_row(u, i, b, r);
        Row8 t;
        t.a = er[2 * q];
        t.b = er[2 * q + 1];
        return t;
    }
    static __device__ __forceinline__ void fma(float4& s0, float4& s1, type w, float v) {
        s0.x = fmaf(w.a.x, v, s0.x);
        s0.y = fmaf(w.a.y, v, s0.y);
        s0.z = fmaf(w.a.z, v, s0.z);
        s0.w = fmaf(w.a.w, v, s0.w);
        s1.x = fmaf(w.b.x, v, s1.x);
        s1.y = fmaf(w.b.y, v, s1.y);
        s1.z = fmaf(w.b.z, v, s1.z);
        s1.w = fmaf(w.b.w, v, s1.w);
    }
};

// ---------------------------------------------------------------------------
// gather SpMM: 8 lanes per dst node (8 dims/lane), 8 nodes per wave.
// Edge loop unrolled x2 with independent accumulator pairs: 2 rows in
// flight per iteration, ceil(deg/2) serial iterations (mean deg ~4 -> ~2).
// Odd tail: clamped row index + v=0 multiplier (clamped loads read real
// finite rows, so 0*x is exact). Recs prefetched 4 ahead.
// LAYER=1: ego(fp32)->h1(bf16). LAYER=2: h1->h2. LAYER=3: h2 -> fused
// out = (ego + h1 + h2 + sum) * 0.25.
// ---------------------------------------------------------------------------
template <int LAYER>
__global__ void lgcn_gather(const int*   __restrict__ rowptr,
                            const uint2* __restrict__ csr,
                            const uint4* __restrict__ h_src,
                            const float* __restrict__ user,
                            const float* __restrict__ item,
                            const float* __restrict__ brand,
                            const uint4* __restrict__ h1,
                            const uint4* __restrict__ h2,
                            uint4*       __restrict__ h_out,
                            float*       __restrict__ out) {
    typedef typename RowStore<LAYER>::type RowT;
    int g    = blockIdx.x * blockDim.x + threadIdx.x;   // node*8 + q
    int node = g >> 3;
    int q    = g & 7;
    int beg = rowptr[node];
    int end = rowptr[node + 1];
    float4 s0 = make_float4(0.f, 0.f, 0.f, 0.f);
    float4 s1 = make_float4(0.f, 0.f, 0.f, 0.f);
    float4 t0 = make_float4(0.f, 0.f, 0.f, 0.f);
    float4 t1 = make_float4(0.f, 0.f, 0.f, 0.f);
    if (beg < end) {
        int last = end - 1;
        uint2 r0 = csr[beg];
        uint2 r1 = csr[beg + 1 < end ? beg + 1 : last];
        uint2 r2 = csr[beg + 2 < end ? beg + 2 : last];
        uint2 r3 = csr[beg + 3 < end ? beg + 3 : last];
        RowT wA = RowStore<LAYER>::load(h_src, user, item, brand, (int)r0.x, q);
        RowT wB = RowStore<LAYER>::load(h_src, user, item, brand, (int)r1.x, q);
        for (int j = beg; j < end; j += 2) {
            uint2 r4 = csr[j + 4 < end ? j + 4 : last];  // recs, 4 ahead
            uint2 r5 = csr[j + 5 < end ? j + 5 : last];
            RowT wC = RowStore<LAYER>::load(h_src, user, item, brand, (int)r2.x, q);
            RowT wD = RowStore<LAYER>::load(h_src, user, item, brand, (int)r3.x, q);
            float vA = __uint_as_float(r0.y);
            float vB = (j + 1 < end) ? __uint_as_float(r1.y) : 0.f;
            RowStore<LAYER>::fma(s0, s1, wA, vA);
            RowStore<LAYER>::fma(t0, t1, wB, vB);
            r0 = r2; r1 = r3; r2 = r4; r3 = r5;
            wA = wC; wB = wD;
        }
        s0.x += t0.x; s0.y += t0.y; s0.z += t0.z; s0.w += t0.w;
        s1.x += t1.x; s1.y += t1.y; s1.z += t1.z; s1.w += t1.w;
    }
    if (LAYER != 3) {
        uint4 w;
        w.x = pack_bf(s0.x, s0.y);
        w.y = pack_bf(s0.z, s0.w);
        w.z = pack_bf(s1.x, s1.y);
        w.w = pack_bf(s1.z, s1.w);
        h_out[g] = w;
    } else if (node < OUT_ROWS) {
        const float4* er = ego_row(user, item, brand, node);
        float4 e0 = er[2 * q];
        float4 e1 = er[2 * q + 1];
        uint4 w1 = h1[g];
        uint4 w2 = h2[g];
        float4 o0, o1;
        o0.x = (e0.x + bf_lo(w1.x) + bf_lo(w2.x) + s0.x) * 0.25f;
        o0.y = (e0.y + bf_hi(w1.x) + bf_hi(w2.x) + s0.y) * 0.25f;
        o0.z = (e0.z + bf_lo(w1.y) + bf_lo(w2.y) + s0.z) * 0.25f;
        o0.w = (e0.w + bf_hi(w1.y) + bf_hi(w2.y) + s0.w) * 0.25f;
        o1.x = (e1.x + bf_lo(w1.z) + bf_lo(w2.z) + s1.x) * 0.25f;
        o1.y = (e1.y + bf_hi(w1.z) + bf_hi(w2.z) + s1.y) * 0.25f;
        o1.z = (e1.z + bf_lo(w1.w) + bf_lo(w2.w) + s1.z) * 0.25f;
        o1.w = (e1.w + bf_hi(w1.w) + bf_hi(w2.w) + s1.w) * 0.25f;
        float4* o = reinterpret_cast<float4*>(out) + g * 2;
        o[0] = o0;
        o[1] = o1;
    }
}

extern "C" void kernel_launch(void* const* d_in, const int* in_sizes, int n_in,
                              void* d_out, int out_size, void* d_ws, size_t ws_size,
                              hipStream_t stream) {
    const float* user  = (const float*)d_in[0];
    const float* item  = (const float*)d_in[1];
    const float* brand = (const float*)d_in[2];
    const float* vals  = (const float*)d_in[3];
    const int*   src   = (const int*)d_in[4];
    const int*   dst   = (const int*)d_in[5];
    float* out = (float*)d_out;

    // workspace layout (32-bit words); 16B alignment holds for uint4 arrays
    size_t W = 0;
    uint4* h1  = (uint4*)d_ws;                 W += (size_t)N_NODES * 32;   // bf16 rows (128B)
    uint4* h2  = (uint4*)((int*)d_ws + W);     W += (size_t)N_NODES * 32;
    uint2* csr = (uint2*)((int*)d_ws + W);     W += (size_t)N_EDGES * 2;
    int* rank      = (int*)d_ws + W;           W += N_EDGES;
    int* pos       = (int*)d_ws + W;           W += N_EDGES;
    int* rowptr    = (int*)d_ws + W;           W += N_NODES + 2;
    int* counts    = (int*)d_ws + W;           W += N_NODES;       // memset
    int* blockSums = (int*)d_ws + W;           W += 512;
    (void)ws_size; (void)n_in; (void)in_sizes; (void)out_size;

    const int edgeBlocks   = (N_EDGES + 255) / 256;     // 4688
    const int gatherBlocks = (N_NODES * 8) / 256;       // 9375 (8 thr/node)

    // zero degree counters (workspace is poisoned; hist accumulates)
    hipMemsetAsync(counts, 0, (size_t)N_NODES * sizeof(int), stream);

    // build dst-sorted CSR: hist+rank -> scan -> pos -> XCD-binned scatter
    lgcn_hist   <<<edgeBlocks, 256, 0, stream>>>(dst, counts, rank);
    lgcn_scan_p1<<<NB, 256, 0, stream>>>(counts, rowptr, blockSums);
    lgcn_scan_p2<<<1, 512, 0, stream>>>(blockSums);
    lgcn_scan_p3<<<NB, 256, 0, stream>>>(rowptr, blockSums);
    lgcn_pos    <<<edgeBlocks, 256, 0, stream>>>(dst, rank, rowptr, pos);
    lgcn_csr_bin<<<NBIN * edgeBlocks, 256, 0, stream>>>(src, vals, pos, csr);

    // 3 atomic-free SpMM layers (bf16 intermediates); residual fused in L3
    lgcn_gather<1><<<gatherBlocks, 256, 0, stream>>>(rowptr, csr, nullptr, user, item,
                                                     brand, h1, h2, h1, out);
    lgcn_gather<2><<<gatherBlocks, 256, 0, stream>>>(rowptr, csr, h1, user, item,
                                                     brand, h1, h2, h2, out);
    lgcn_gather<3><<<gatherBlocks, 256, 0, stream>>>(rowptr, csr, h2, user, item,
                                                     brand, h1, h2, nullptr, out);
}